// Round 1
// baseline (440.900 us; speedup 1.0000x reference)
//
#include <hip/hip_runtime.h>

// low_rank multimodal fusion: B=131072, IN=128 (+bias row -> K=129), OUT=128, RANK=4.
// out[b,o] = bias[o] + sum_r w[r] * prod_m ( factor_m[r,0,o] + sum_k x[b,m,k]*factor_m[r,k+1,o] )
// Strategy: f16 MFMA (16x16x32) GEMMs, factors pre-packed to B-frag layout in d_ws,
// A loaded direct global->reg (fp32->fp16), rank-product fusion in registers.

typedef _Float16 half8 __attribute__((ext_vector_type(8)));
typedef float f32x4 __attribute__((ext_vector_type(4)));

#define NB 131072L
#define OUT_OFF (NB * 128L)

static __device__ inline f32x4 splat4(float s) { return (f32x4){s, s, s, s}; }

// ---------------- prep: pack factors (fp32, [r,129,128]) into f16 MFMA-B fragments ----
// packed frag index: ((m*4 + r)*8 + ot)*4 + ks ; within frag: lane-major, 8 halfs/lane.
// B-frag lane mapping (16x16x32): n = lane&15, k = (lane>>4)*8 + j  (factor row = k+1).
__global__ void pack_b_kernel(const float* __restrict__ af, const float* __restrict__ vf,
                              const float* __restrict__ tf, _Float16* __restrict__ bpk) {
  int t = blockIdx.x * 256 + threadIdx.x;  // [0, 24576)
  int l = t & 63;
  int ks = (t >> 6) & 3;
  int ot = (t >> 8) & 7;
  int r = (t >> 11) & 3;
  int m = t >> 13;
  const float* f = (m == 0) ? af : ((m == 1) ? vf : tf);
  int i0 = 1 + ks * 32 + (l >> 4) * 8;
  int o = ot * 16 + (l & 15);
  half8 v;
#pragma unroll
  for (int j = 0; j < 8; ++j) v[j] = (_Float16)f[(r * 129 + i0 + j) * 128 + o];
  *(half8*)(bpk + (size_t)t * 8) = v;
}

// ---------------- main fused kernel -------------------------------------------------
// grid: 1024 blocks x 256 threads; wave W = blockIdx*4 + (tid>>6) owns rows [W*32, W*32+32)
__global__ __launch_bounds__(256, 2) void lmf_main(
    const float* __restrict__ x, const float* __restrict__ af, const float* __restrict__ vf,
    const float* __restrict__ tf, const float* __restrict__ fw, const float* __restrict__ fb,
    const _Float16* __restrict__ bpk, float* __restrict__ out) {
  const int lane = threadIdx.x & 63;
  const int wv = threadIdx.x >> 6;
  const int W = blockIdx.x * 4 + wv;
  const long row0 = (long)W * 32;
  const int m16 = lane & 15;  // A row within tile / C col
  const int q = lane >> 4;    // k-octet selector / C row-quad

  // ---- A fragments: a[mt][mod][ks], 8 halfs each (96 VGPRs total), fp32->fp16 RTN
  half8 a[2][3][4];
#pragma unroll
  for (int mt = 0; mt < 2; ++mt) {
    const float* xs = x + (row0 + mt * 16 + m16) * 384 + q * 8;
#pragma unroll
    for (int mod = 0; mod < 3; ++mod) {
#pragma unroll
      for (int ks = 0; ks < 4; ++ks) {
        const float* p = xs + mod * 128 + ks * 32;
        f32x4 p0 = __builtin_nontemporal_load((const f32x4*)p);
        f32x4 p1 = __builtin_nontemporal_load((const f32x4*)(p + 4));
#pragma unroll
        for (int j = 0; j < 4; ++j) {
          a[mt][mod][ks][j] = (_Float16)p0[j];
          a[mt][mod][ks][4 + j] = (_Float16)p1[j];
        }
      }
    }
  }

  const float wr0 = fw[0], wr1 = fw[1], wr2 = fw[2], wr3 = fw[3];
  const float wr[4] = {wr0, wr1, wr2, wr3};

  float* po0 = out + (row0 + q * 4) * 128 + m16;        // mt=0, copy 0
  float* po1 = out + (row0 + 16 + q * 4) * 128 + m16;   // mt=1, copy 0
  float* qo0 = po0 + OUT_OFF;                           // copy 1
  float* qo1 = po1 + OUT_OFF;

  for (int ot = 0; ot < 8; ++ot) {
    const int ocol = ot * 16 + m16;
    f32x4 oacc[2];
    oacc[0] = splat4(fb[ocol]);
    oacc[1] = oacc[0];
#pragma unroll
    for (int r = 0; r < 4; ++r) {
      // bias-row of each factor folded in as MFMA C-init (per-lane col-dependent)
      f32x4 acc[3][2];
      acc[0][0] = splat4(af[r * 16512 + ocol]);
      acc[1][0] = splat4(vf[r * 16512 + ocol]);
      acc[2][0] = splat4(tf[r * 16512 + ocol]);
      acc[0][1] = acc[0][0];
      acc[1][1] = acc[1][0];
      acc[2][1] = acc[2][0];
#pragma unroll
      for (int mod = 0; mod < 3; ++mod) {
        const _Float16* bb = bpk + (size_t)(((mod * 4 + r) * 8 + ot) * 4) * 512 + lane * 8;
#pragma unroll
        for (int ks = 0; ks < 4; ++ks) {
          half8 bf = *(const half8*)(bb + ks * 512);
          acc[mod][0] =
              __builtin_amdgcn_mfma_f32_16x16x32_f16(a[0][mod][ks], bf, acc[mod][0], 0, 0, 0);
          acc[mod][1] =
              __builtin_amdgcn_mfma_f32_16x16x32_f16(a[1][mod][ks], bf, acc[mod][1], 0, 0, 0);
        }
      }
#pragma unroll
      for (int mt = 0; mt < 2; ++mt) {
#pragma unroll
        for (int g = 0; g < 4; ++g) {
          float pa = acc[0][mt][g];
          float pv = acc[1][mt][g];
          float pt = acc[2][mt][g];
          oacc[mt][g] += wr[r] * (pa * pv * pt);
        }
      }
    }
    // C/D layout: col = lane&15, row = q*4 + g
#pragma unroll
    for (int g = 0; g < 4; ++g) {
      __builtin_nontemporal_store(oacc[0][g], po0 + ot * 16 + g * 128);
      __builtin_nontemporal_store(oacc[1][g], po1 + ot * 16 + g * 128);
      __builtin_nontemporal_store(oacc[0][g], qo0 + ot * 16 + g * 128);
      __builtin_nontemporal_store(oacc[1][g], qo1 + ot * 16 + g * 128);
    }
  }
}

// ---------------- fallback (only if d_ws is too small): correct fp32 vector version --
__global__ void lmf_fallback(const float* __restrict__ x, const float* __restrict__ af,
                             const float* __restrict__ vf, const float* __restrict__ tf,
                             const float* __restrict__ fw, const float* __restrict__ fb,
                             float* __restrict__ out) {
  long b = blockIdx.x;
  int o = threadIdx.x;  // 128 threads
  __shared__ float xr[384];
  for (int i = threadIdx.x; i < 384; i += 128) xr[i] = x[b * 384 + i];
  __syncthreads();
  float acc = fb[o];
  for (int r = 0; r < 4; ++r) {
    const float* A = af + (long)r * 16512 + o;
    const float* V = vf + (long)r * 16512 + o;
    const float* T = tf + (long)r * 16512 + o;
    float sa = A[0], sv = V[0], st = T[0];
    for (int i = 0; i < 128; ++i) {
      sa += xr[i] * A[(i + 1) * 128];
      sv += xr[128 + i] * V[(i + 1) * 128];
      st += xr[256 + i] * T[(i + 1) * 128];
    }
    acc += fw[r] * sa * sv * st;
  }
  out[b * 128 + o] = acc;
  out[OUT_OFF + b * 128 + o] = acc;
}

extern "C" void kernel_launch(void* const* d_in, const int* in_sizes, int n_in, void* d_out,
                              int out_size, void* d_ws, size_t ws_size, hipStream_t stream) {
  const float* x = (const float*)d_in[0];
  const float* af = (const float*)d_in[1];
  const float* vf = (const float*)d_in[2];
  const float* tf = (const float*)d_in[3];
  const float* fw = (const float*)d_in[4];
  const float* fb = (const float*)d_in[5];
  float* out = (float*)d_out;

  const size_t need = 24576 * 8 * sizeof(_Float16);  // 384 KiB packed B
  if (ws_size >= need) {
    pack_b_kernel<<<96, 256, 0, stream>>>(af, vf, tf, (_Float16*)d_ws);
    lmf_main<<<1024, 256, 0, stream>>>(x, af, vf, tf, fw, fb, (const _Float16*)d_ws, out);
  } else {
    lmf_fallback<<<dim3(131072), 128, 0, stream>>>(x, af, vf, tf, fw, fb, out);
  }
}

// Round 2
// 377.646 us; speedup vs baseline: 1.1675x; 1.1675x over previous
//
#include <hip/hip_runtime.h>

// low_rank multimodal fusion: B=131072, IN=128 (+bias row -> K=129), OUT=128, RANK=4.
// out[b,o] = bias[o] + sum_r w[r] * prod_m ( factor_m[r,0,o] + sum_k x[b,m,k]*factor_m[r,k+1,o] )
// R2: B-fragments staged per-ot into LDS (48 KB) via global_load_lds width=16;
//     inner MFMA loop reads LDS (ds_read_b128) instead of L2. 3 blocks/CU.

typedef _Float16 half8 __attribute__((ext_vector_type(8)));
typedef float f32x4 __attribute__((ext_vector_type(4)));

#define NB 131072L
#define OUT_OFF (NB * 128L)

static __device__ inline f32x4 splat4(float s) { return (f32x4){s, s, s, s}; }

// ---------------- prep: pack factors (fp32, [r,129,128]) into f16 MFMA-B fragments ----
// packed frag index: ((m*4 + r)*8 + ot)*4 + ks ; within frag: lane-major, 8 halfs/lane.
// B-frag lane mapping (16x16x32): n = lane&15, k = (lane>>4)*8 + j  (factor row = k+1).
__global__ void pack_b_kernel(const float* __restrict__ af, const float* __restrict__ vf,
                              const float* __restrict__ tf, _Float16* __restrict__ bpk) {
  int t = blockIdx.x * 256 + threadIdx.x;  // [0, 24576)
  int l = t & 63;
  int ks = (t >> 6) & 3;
  int ot = (t >> 8) & 7;
  int r = (t >> 11) & 3;
  int m = t >> 13;
  const float* f = (m == 0) ? af : ((m == 1) ? vf : tf);
  int i0 = 1 + ks * 32 + (l >> 4) * 8;
  int o = ot * 16 + (l & 15);
  half8 v;
#pragma unroll
  for (int j = 0; j < 8; ++j) v[j] = (_Float16)f[(r * 129 + i0 + j) * 128 + o];
  *(half8*)(bpk + (size_t)t * 8) = v;
}

// ---------------- main fused kernel -------------------------------------------------
// grid: 1024 blocks x 256 threads; wave W = blockIdx*4 + (tid>>6) owns rows [W*32, W*32+32)
__global__ __launch_bounds__(256, 3) void lmf_main(
    const float* __restrict__ x, const float* __restrict__ af, const float* __restrict__ vf,
    const float* __restrict__ tf, const float* __restrict__ fw, const float* __restrict__ fb,
    const _Float16* __restrict__ bpk, float* __restrict__ out) {
  // 48 KB: per-ot B fragments, frag f=(mod*4+r)*4+ks, 512 halfs (1 KB) per frag
  __shared__ _Float16 bl[48 * 512];

  const int lane = threadIdx.x & 63;
  const int wv = threadIdx.x >> 6;
  const int W = blockIdx.x * 4 + wv;
  const long row0 = (long)W * 32;
  const int m16 = lane & 15;  // A row within tile / C col
  const int q = lane >> 4;    // k-octet selector / C row-quad

  // ---- A fragments: a[mt][mod][ks], 8 halfs each (96 VGPRs), fp32->fp16 RTN
  half8 a[2][3][4];
#pragma unroll
  for (int mt = 0; mt < 2; ++mt) {
    const float* xs = x + (row0 + mt * 16 + m16) * 384 + q * 8;
#pragma unroll
    for (int mod = 0; mod < 3; ++mod) {
#pragma unroll
      for (int ks = 0; ks < 4; ++ks) {
        const float* p = xs + mod * 128 + ks * 32;
        f32x4 p0 = __builtin_nontemporal_load((const f32x4*)p);
        f32x4 p1 = __builtin_nontemporal_load((const f32x4*)(p + 4));
#pragma unroll
        for (int j = 0; j < 4; ++j) {
          a[mt][mod][ks][j] = (_Float16)p0[j];
          a[mt][mod][ks][4 + j] = (_Float16)p1[j];
        }
      }
    }
  }

  const float wr0 = fw[0], wr1 = fw[1], wr2 = fw[2], wr3 = fw[3];
  const float wr[4] = {wr0, wr1, wr2, wr3};

  float* po0 = out + (row0 + q * 4) * 128 + m16;       // mt=0, copy 0
  float* po1 = out + (row0 + 16 + q * 4) * 128 + m16;  // mt=1, copy 0
  float* qo0 = po0 + OUT_OFF;                          // copy 1
  float* qo1 = po1 + OUT_OFF;

  for (int ot = 0; ot < 8; ++ot) {
    // ---- stage this ot's 48 KB of B-fragments into LDS (async, width=16) ----
    // region i=(mod*4+r) is 4 KB contiguous in bpk at byte (i*8+ot)*4096;
    // block covers each region in one pass: thread t -> bytes t*16..t*16+15.
    // LDS dst = wave-uniform base (i*4096 + wv*1024) + lane*16  -- layout matches HW.
#pragma unroll
    for (int i = 0; i < 12; ++i) {
      const _Float16* gp = bpk + (size_t)(((i * 8 + ot) * 2048) + wv * 512 + lane * 8);
      _Float16* lp = bl + (i * 2048 + wv * 512 + lane * 8);
      __builtin_amdgcn_global_load_lds((const __attribute__((address_space(1))) void*)gp,
                                       (__attribute__((address_space(3))) void*)lp, 16, 0, 0);
    }
    __syncthreads();  // drains vmcnt -> LDS valid for all waves

    const int ocol = ot * 16 + m16;
    f32x4 oacc[2];
    oacc[0] = splat4(fb[ocol]);
    oacc[1] = oacc[0];
#pragma unroll
    for (int r = 0; r < 4; ++r) {
      // bias-row of each factor folded in as MFMA C-init (per-lane col-dependent)
      f32x4 acc[3][2];
      acc[0][0] = splat4(af[r * 16512 + ocol]);
      acc[1][0] = splat4(vf[r * 16512 + ocol]);
      acc[2][0] = splat4(tf[r * 16512 + ocol]);
      acc[0][1] = acc[0][0];
      acc[1][1] = acc[1][0];
      acc[2][1] = acc[2][0];
#pragma unroll
      for (int mod = 0; mod < 3; ++mod) {
        const _Float16* bb = bl + ((mod * 4 + r) * 4) * 512 + lane * 8;
#pragma unroll
        for (int ks = 0; ks < 4; ++ks) {
          half8 bf = *(const half8*)(bb + ks * 512);  // ds_read_b128, conflict-free
          acc[mod][0] =
              __builtin_amdgcn_mfma_f32_16x16x32_f16(a[0][mod][ks], bf, acc[mod][0], 0, 0, 0);
          acc[mod][1] =
              __builtin_amdgcn_mfma_f32_16x16x32_f16(a[1][mod][ks], bf, acc[mod][1], 0, 0, 0);
        }
      }
#pragma unroll
      for (int mt = 0; mt < 2; ++mt) {
#pragma unroll
        for (int g = 0; g < 4; ++g) {
          float pa = acc[0][mt][g];
          float pv = acc[1][mt][g];
          float pt = acc[2][mt][g];
          oacc[mt][g] += wr[r] * (pa * pv * pt);
        }
      }
    }
    // C/D layout: col = lane&15, row = q*4 + g
#pragma unroll
    for (int g = 0; g < 4; ++g) {
      __builtin_nontemporal_store(oacc[0][g], po0 + ot * 16 + g * 128);
      __builtin_nontemporal_store(oacc[1][g], po1 + ot * 16 + g * 128);
      __builtin_nontemporal_store(oacc[0][g], qo0 + ot * 16 + g * 128);
      __builtin_nontemporal_store(oacc[1][g], qo1 + ot * 16 + g * 128);
    }
    __syncthreads();  // LDS reads done before next ot's stage overwrites
  }
}

// ---------------- fallback (only if d_ws is too small): correct fp32 vector version --
__global__ void lmf_fallback(const float* __restrict__ x, const float* __restrict__ af,
                             const float* __restrict__ vf, const float* __restrict__ tf,
                             const float* __restrict__ fw, const float* __restrict__ fb,
                             float* __restrict__ out) {
  long b = blockIdx.x;
  int o = threadIdx.x;  // 128 threads
  __shared__ float xr[384];
  for (int i = threadIdx.x; i < 384; i += 128) xr[i] = x[b * 384 + i];
  __syncthreads();
  float acc = fb[o];
  for (int r = 0; r < 4; ++r) {
    const float* A = af + (long)r * 16512 + o;
    const float* V = vf + (long)r * 16512 + o;
    const float* T = tf + (long)r * 16512 + o;
    float sa = A[0], sv = V[0], st = T[0];
    for (int i = 0; i < 128; ++i) {
      sa += xr[i] * A[(i + 1) * 128];
      sv += xr[128 + i] * V[(i + 1) * 128];
      st += xr[256 + i] * T[(i + 1) * 128];
    }
    acc += fw[r] * sa * sv * st;
  }
  out[b * 128 + o] = acc;
  out[OUT_OFF + b * 128 + o] = acc;
}

extern "C" void kernel_launch(void* const* d_in, const int* in_sizes, int n_in, void* d_out,
                              int out_size, void* d_ws, size_t ws_size, hipStream_t stream) {
  const float* x = (const float*)d_in[0];
  const float* af = (const float*)d_in[1];
  const float* vf = (const float*)d_in[2];
  const float* tf = (const float*)d_in[3];
  const float* fw = (const float*)d_in[4];
  const float* fb = (const float*)d_in[5];
  float* out = (float*)d_out;

  const size_t need = 24576 * 8 * sizeof(_Float16);  // 384 KiB packed B
  if (ws_size >= need) {
    pack_b_kernel<<<96, 256, 0, stream>>>(af, vf, tf, (_Float16*)d_ws);
    lmf_main<<<1024, 256, 0, stream>>>(x, af, vf, tf, fw, fb, (const _Float16*)d_ws, out);
  } else {
    lmf_fallback<<<dim3(131072), 128, 0, stream>>>(x, af, vf, tf, fw, fb, out);
  }
}